// Round 7
// baseline (174.159 us; speedup 1.0000x reference)
//
#include <hip/hip_runtime.h>
#include <hip/hip_bf16.h>

#define HCn 4
#define Cn 2048
#define Dn (HCn*Cn)       // 8192
#define NLg 24            // HC*HC + 2*HC
#define TMAXn 8

typedef short bf16x8 __attribute__((ext_vector_type(8)));
typedef float f32x4 __attribute__((ext_vector_type(4)));

__device__ __forceinline__ unsigned int pk2(float a, float b) {
  union { __hip_bfloat162 h; unsigned int u; } v;
  v.h = __float22bfloat162_rn(float2{a, b});
  return v.u;
}
__device__ __forceinline__ unsigned short f2bfu(float a) {
  union { __hip_bfloat16 h; unsigned short u; } v;
  v.h = __float2bfloat16(a);
  return v.u;
}
__device__ __forceinline__ float bf2f(unsigned int u16) {
  union { float f; unsigned int x; } v;
  v.x = u16 << 16;
  return v.f;
}
__device__ __forceinline__ void unpack8(uint4 v, float* o) {
  o[0] = bf2f(v.x & 0xffffu); o[1] = bf2f(v.x >> 16);
  o[2] = bf2f(v.y & 0xffffu); o[3] = bf2f(v.y >> 16);
  o[4] = bf2f(v.z & 0xffffu); o[5] = bf2f(v.z >> 16);
  o[6] = bf2f(v.w & 0xffffu); o[7] = bf2f(v.w >> 16);
}
__device__ __forceinline__ float sigm(float z) { return 1.0f / (1.0f + expf(-z)); }

__device__ __forceinline__ void gload_lds16(const void* g, void* l) {
  __builtin_amdgcn_global_load_lds((__attribute__((address_space(1))) void*)(g),
                                   (__attribute__((address_space(3))) void*)(l),
                                   16, 0, 0);
}

// ---------------- Kernel 0: phi [8192][24] -> phiB B-fragment layout (bf16) ----------
__global__ __launch_bounds__(128) void phib_kernel(const float* __restrict__ phi,
                                                   unsigned short* __restrict__ phiB) {
  int tid = threadIdx.x;
  int nt = tid >> 6, lane = tid & 63;
  int ks = blockIdx.x;
  int col = nt * 16 + (lane & 15);
  int kb = ks * 32 + (lane >> 4) * 8;
  float v[8];
#pragma unroll
  for (int e = 0; e < 8; ++e)
    v[e] = (col < NLg) ? phi[(size_t)(kb + e) * NLg + col] : 0.f;
  uint4 o = { pk2(v[0], v[1]), pk2(v[2], v[3]), pk2(v[4], v[5]), pk2(v[6], v[7]) };
  *(uint4*)&phiB[((size_t)(ks * 2 + nt) * 64 + lane) * 8] = o;
}

// ------- Kernel 1: split-K logits partials + x->bf16 transcode.
// 1024 blocks = 256 tok-groups x 4 K-chunks; 8 waves; wave K-window 256.
__global__ __launch_bounds__(512) void logits_kernel(
    const float* __restrict__ x, const unsigned short* __restrict__ phiB,
    float* __restrict__ pbuf, unsigned int* __restrict__ xbf) {
  __shared__ float lgp[8][16][33];
  __shared__ float ssp[8][16];

  int tid = threadIdx.x, lane = tid & 63, wid = tid >> 6;
  int g = blockIdx.x >> 2;        // token group (16 tokens)
  int kc = blockIdx.x & 3;        // K-chunk (2048 wide)
  long t0 = (long)g * 16;
  int l15 = lane & 15, kg = lane >> 4;

  int kbase = kc * 2048 + wid * 256;
  const float* xr = x + (size_t)(t0 + l15) * Dn + kbase + kg * 8;
  uint4* xw4 = (uint4*)xbf + ((size_t)(t0 + l15) * 1024 + (kbase >> 3) + kg);
  const bf16x8* pB = (const bf16x8*)phiB + (size_t)(kbase >> 5) * 128 + lane;

  float ss = 0.f;
  f32x4 acc0 = {0.f,0.f,0.f,0.f}, acc1 = {0.f,0.f,0.f,0.f};

  float4 A0[3], A1[3]; bf16x8 Bv0[3], Bv1[3];
#define LOADIT(IT, S) {                          \
    A0[S] = *(const float4*)(xr + (IT) * 32);    \
    A1[S] = *(const float4*)(xr + (IT) * 32 + 4);\
    Bv0[S] = pB[(IT) * 128];                     \
    Bv1[S] = pB[(IT) * 128 + 64]; }
#define PROCIT(S, IT) {                                                       \
    float4 P0 = A0[S], P1 = A1[S];                                            \
    ss += P0.x*P0.x + P0.y*P0.y + P0.z*P0.z + P0.w*P0.w;                      \
    ss += P1.x*P1.x + P1.y*P1.y + P1.z*P1.z + P1.w*P1.w;                      \
    uint4 u_ = { pk2(P0.x,P0.y), pk2(P0.z,P0.w), pk2(P1.x,P1.y), pk2(P1.z,P1.w) }; \
    xw4[(IT) * 4] = u_;                                                       \
    bf16x8 a_ = *(bf16x8*)&u_;                                                \
    acc0 = __builtin_amdgcn_mfma_f32_16x16x32_bf16(a_, Bv0[S], acc0, 0, 0, 0);\
    acc1 = __builtin_amdgcn_mfma_f32_16x16x32_bf16(a_, Bv1[S], acc1, 0, 0, 0); }

  LOADIT(0, 0); LOADIT(1, 1);
#pragma unroll
  for (int it = 0; it < 8; ++it) {
    if (it < 6) LOADIT(it + 2, (it + 2) % 3);
    PROCIT(it % 3, it);
  }
#undef LOADIT
#undef PROCIT

  ss += __shfl_xor(ss, 16); ss += __shfl_xor(ss, 32);
  if (kg == 0) ssp[wid][l15] = ss;
#pragma unroll
  for (int e = 0; e < 4; ++e) {
    int tok = kg * 4 + e;
    lgp[wid][tok][l15] = acc0[e];
    lgp[wid][tok][16 + l15] = acc1[e];
  }
  __syncthreads();

  for (int q = tid; q < 16 * 25; q += 512) {
    int tk = q / 25, j = q % 25;
    float v = 0.f;
    if (j < 24) {
#pragma unroll
      for (int w = 0; w < 8; ++w) v += lgp[w][tk][j];
    } else {
#pragma unroll
      for (int w = 0; w < 8; ++w) v += ssp[w][tk];
    }
    pbuf[(size_t)(t0 + tk) * 100 + kc * 25 + j] = v;
  }
}

// ------- Kernel 1b: finalize — sum 4 K-chunks, sigmoid/Sinkhorn, emit coeffs ---------
__global__ __launch_bounds__(256) void finalize_kernel(
    const float* __restrict__ pbuf, const float* __restrict__ bb,
    const float* __restrict__ apre_p, const float* __restrict__ apost_p,
    const float* __restrict__ ares_p, float* __restrict__ hpre,
    float* __restrict__ hpost, float* __restrict__ hres) {
  long t = (long)blockIdx.x * 256 + threadIdx.x;
  const float* pt = pbuf + (size_t)t * 100;
  float lg[25];
#pragma unroll
  for (int j = 0; j < 25; ++j)
    lg[j] = pt[j] + pt[25 + j] + pt[50 + j] + pt[75 + j];
  float r = rsqrtf(lg[24] / (float)Dn + 1e-6f);
  float apre = apre_p[0], apost = apost_p[0], ares = ares_p[0];
#pragma unroll
  for (int j = 0; j < NLg; ++j) lg[j] = r * lg[j] + bb[j];
#pragma unroll
  for (int j = 0; j < 4; ++j) hpre[t * 4 + j] = sigm(apre * lg[j]) + 1e-4f;
#pragma unroll
  for (int j = 0; j < 4; ++j) hpost[t * 4 + j] = 2.0f * sigm(apost * lg[4 + j]);
  float m[16];
#pragma unroll
  for (int q = 0; q < 16; ++q) m[q] = expf(ares * lg[8 + q]);
  for (int it = 0; it < TMAXn; ++it) {
#pragma unroll
    for (int o = 0; o < 4; ++o) {
      float rs = m[o*4] + m[o*4+1] + m[o*4+2] + m[o*4+3] + 1e-6f;
      m[o*4] /= rs; m[o*4+1] /= rs; m[o*4+2] /= rs; m[o*4+3] /= rs;
    }
#pragma unroll
    for (int i = 0; i < 4; ++i) {
      float cs = m[i] + m[4+i] + m[8+i] + m[12+i] + 1e-6f;
      m[i] /= cs; m[4+i] /= cs; m[8+i] /= cs; m[12+i] /= cs;
    }
  }
#pragma unroll
  for (int q = 0; q < 16; ++q) hres[t * 16 + q] = m[q];
}

// ------- Kernel 1c: x_in from bf16 x (one token per block) ---------------------------
__global__ __launch_bounds__(256) void xin_kernel(
    const unsigned int* __restrict__ xbf, const float* __restrict__ hpre,
    unsigned int* __restrict__ xin) {
  long t = blockIdx.x;
  int tid = threadIdx.x;
  float h0 = hpre[t * 4 + 0], h1 = hpre[t * 4 + 1];
  float h2 = hpre[t * 4 + 2], h3 = hpre[t * 4 + 3];
  const uint4* xb = (const uint4*)xbf + (size_t)t * 1024;
  uint4 v0 = xb[tid], v1 = xb[256 + tid], v2 = xb[512 + tid], v3 = xb[768 + tid];
  float X0[8], X1[8], X2[8], X3[8];
  unpack8(v0, X0); unpack8(v1, X1); unpack8(v2, X2); unpack8(v3, X3);
  float s[8];
#pragma unroll
  for (int e = 0; e < 8; ++e) s[e] = h0*X0[e] + h1*X1[e] + h2*X2[e] + h3*X3[e];
  uint4 o = { pk2(s[0], s[1]), pk2(s[2], s[3]), pk2(s[4], s[5]), pk2(s[6], s[7]) };
  ((uint4*)xin)[(size_t)t * 256 + tid] = o;
}

// ---------------- Kernel 2: W (K x N, f32) -> Wt (N x K, bf16) ----------------
__global__ __launch_bounds__(256) void wtrans_kernel(const float* __restrict__ W,
                                                     unsigned short* __restrict__ Wt) {
  __shared__ float tile[64][65];
  int kb = blockIdx.y * 64, nb = blockIdx.x * 64;
  int tr = threadIdx.x >> 4;
  int tc = threadIdx.x & 15;
#pragma unroll
  for (int rr = 0; rr < 64; rr += 16) {
    float4 v = *(const float4*)&W[(size_t)(kb + tr + rr) * Cn + nb + tc * 4];
    tile[tr + rr][tc * 4 + 0] = v.x; tile[tr + rr][tc * 4 + 1] = v.y;
    tile[tr + rr][tc * 4 + 2] = v.z; tile[tr + rr][tc * 4 + 3] = v.w;
  }
  __syncthreads();
#pragma unroll
  for (int rr = 0; rr < 64; rr += 16) {
    int n = nb + tr + rr;
    uint2 o;
    o.x = pk2(tile[tc * 4 + 0][tr + rr], tile[tc * 4 + 1][tr + rr]);
    o.y = pk2(tile[tc * 4 + 2][tr + rr], tile[tc * 4 + 3][tr + rr]);
    *(uint2*)&Wt[(size_t)n * Cn + kb + tc * 4] = o;
  }
}

// ---------------- Kernel 3: bf16 MFMA GEMM; writes f = x_in@W + Wb (bf16) ------------
#define BMt 128
#define BNt 128
#define BKt 32
#define GK Cn
__global__ __launch_bounds__(256) void gemm_kernel(
    const unsigned short* __restrict__ xin, const unsigned short* __restrict__ Wt,
    const float* __restrict__ Wb, unsigned short* __restrict__ f) {
  __shared__ __align__(16) unsigned short As[BMt * BKt];
  __shared__ __align__(16) unsigned short Bs[BNt * BKt];
  int tid = threadIdx.x;
  int lane = tid & 63, wid = tid >> 6;
  int wr = wid >> 1, wc = wid & 1;
  int l15 = lane & 15, l4 = lane >> 4;
  int wg = blockIdx.x;
  wg = (wg & 7) * 64 + (wg >> 3);   // XCD swizzle, 512 % 8 == 0 bijective
  int bx = wg & 15, by = wg >> 4;

  f32x4 acc[4][4];
#pragma unroll
  for (int i = 0; i < 4; ++i)
#pragma unroll
    for (int j = 0; j < 4; ++j) acc[i][j] = {0.f, 0.f, 0.f, 0.f};

  const char* Ab = (const char*)xin + (size_t)by * BMt * GK * 2;
  const char* Bb = (const char*)Wt + (size_t)bx * BNt * GK * 2;
  int off0 = tid * 16, off1 = tid * 16 + 4096;
  int row0 = off0 >> 6, colb0 = off0 & 63;
  int row1 = off1 >> 6, colb1 = off1 & 63;

  for (int k0 = 0; k0 < GK; k0 += BKt) {
    gload_lds16(Ab + (size_t)row0 * (GK * 2) + k0 * 2 + colb0, (char*)As + off0);
    gload_lds16(Ab + (size_t)row1 * (GK * 2) + k0 * 2 + colb1, (char*)As + off1);
    gload_lds16(Bb + (size_t)row0 * (GK * 2) + k0 * 2 + colb0, (char*)Bs + off0);
    gload_lds16(Bb + (size_t)row1 * (GK * 2) + k0 * 2 + colb1, (char*)Bs + off1);
    __syncthreads();
    bf16x8 af[4], bfv[4];
#pragma unroll
    for (int fm = 0; fm < 4; ++fm)
      af[fm] = *(const bf16x8*)&As[(wr * 64 + fm * 16 + l15) * BKt + l4 * 8];
#pragma unroll
    for (int fn = 0; fn < 4; ++fn)
      bfv[fn] = *(const bf16x8*)&Bs[(wc * 64 + fn * 16 + l15) * BKt + l4 * 8];
#pragma unroll
    for (int fm = 0; fm < 4; ++fm)
#pragma unroll
      for (int fn = 0; fn < 4; ++fn)
        acc[fm][fn] = __builtin_amdgcn_mfma_f32_16x16x32_bf16(af[fm], bfv[fn], acc[fm][fn], 0, 0, 0);
    __syncthreads();
  }

  int m0 = by * BMt + wr * 64;
  int n0 = bx * BNt + wc * 64;
#pragma unroll
  for (int fm = 0; fm < 4; ++fm) {
#pragma unroll
    for (int e = 0; e < 4; ++e) {
      int t = m0 + fm * 16 + l4 * 4 + e;
      unsigned short* ft = f + (size_t)t * Cn;
#pragma unroll
      for (int fn = 0; fn < 4; ++fn) {
        int c = n0 + fn * 16 + l15;
        ft[c] = f2bfu(acc[fm][fn][e] + Wb[c]);
      }
    }
  }
}

// ---------------- Kernel 4: streaming epilogue (one token per block, bf16 x) ---------
__global__ __launch_bounds__(256) void epilogue_kernel(
    const unsigned int* __restrict__ xbf, const unsigned short* __restrict__ f,
    const float* __restrict__ hpost, const float* __restrict__ hres,
    float* __restrict__ out) {
  long t = blockIdx.x;
  int tid = threadIdx.x;
  float hq[4], hr[16];
#pragma unroll
  for (int o = 0; o < 4; ++o) hq[o] = hpost[t * 4 + o];
#pragma unroll
  for (int q = 0; q < 16; ++q) hr[q] = hres[t * 16 + q];
  const uint4* xb = (const uint4*)xbf + (size_t)t * 1024;
  const uint4* fb = (const uint4*)f + (size_t)t * 256;
  float* ot = out + (size_t)t * Dn;

  uint4 v0 = xb[tid], v1 = xb[256 + tid], v2 = xb[512 + tid], v3 = xb[768 + tid];
  uint4 fv = fb[tid];
  float X0[8], X1[8], X2[8], X3[8], F[8];
  unpack8(v0, X0); unpack8(v1, X1); unpack8(v2, X2); unpack8(v3, X3);
  unpack8(fv, F);
#pragma unroll
  for (int o = 0; o < 4; ++o) {
    float a = hr[o*4+0], b = hr[o*4+1], c = hr[o*4+2], d = hr[o*4+3], q = hq[o];
    float r[8];
#pragma unroll
    for (int e = 0; e < 8; ++e)
      r[e] = q*F[e] + a*X0[e] + b*X1[e] + c*X2[e] + d*X3[e];
    float4* po = (float4*)&ot[(size_t)o * Cn + tid * 8];
    po[0] = float4{r[0], r[1], r[2], r[3]};
    po[1] = float4{r[4], r[5], r[6], r[7]};
  }
}

extern "C" void kernel_launch(void* const* d_in, const int* in_sizes, int n_in,
                              void* d_out, int out_size, void* d_ws, size_t ws_size,
                              hipStream_t stream) {
  const float* x     = (const float*)d_in[0];
  const float* phi   = (const float*)d_in[1];
  const float* b     = (const float*)d_in[2];
  const float* apre  = (const float*)d_in[3];
  const float* apost = (const float*)d_in[4];
  const float* ares  = (const float*)d_in[5];
  const float* W     = (const float*)d_in[6];
  const float* Wb    = (const float*)d_in[7];
  float* out = (float*)d_out;

  int NT = in_sizes[0] / Dn;   // 4096 tokens
  char* ws = (char*)d_ws;
  size_t off = 0;
  unsigned int*   xin  = (unsigned int*)(ws + off);   off += (size_t)NT * Cn * 2;   // 16 MB
  unsigned short* Wt   = (unsigned short*)(ws + off); off += (size_t)Cn * Cn * 2;   // 8 MB
  float* hpre  = (float*)(ws + off); off += (size_t)NT * 4 * 4;
  float* hpost = (float*)(ws + off); off += (size_t)NT * 4 * 4;
  float* hres  = (float*)(ws + off); off += (size_t)NT * 16 * 4;
  unsigned short* phiB = (unsigned short*)(ws + off); off += (size_t)Dn * 32 * 2;   // 512 KB
  float* pbuf  = (float*)(ws + off); off += (size_t)NT * 100 * 4;                   // 1.6 MB
  unsigned short* fbuf = (unsigned short*)(ws + off); off += (size_t)NT * Cn * 2;   // 16 MB
  unsigned int* xbf    = (unsigned int*)(ws + off);   off += (size_t)NT * Dn * 2;   // 64 MB

  hipLaunchKernelGGL(phib_kernel, dim3(Dn / 32), dim3(128), 0, stream, phi, phiB);
  hipLaunchKernelGGL(logits_kernel, dim3((NT / 16) * 4), dim3(512), 0, stream,
                     x, phiB, pbuf, xbf);
  hipLaunchKernelGGL(finalize_kernel, dim3(NT / 256), dim3(256), 0, stream,
                     pbuf, b, apre, apost, ares, hpre, hpost, hres);
  hipLaunchKernelGGL(xin_kernel, dim3(NT), dim3(256), 0, stream, xbf, hpre, xin);
  hipLaunchKernelGGL(wtrans_kernel, dim3(Cn / 64, Cn / 64), dim3(256), 0, stream, W, Wt);
  hipLaunchKernelGGL(gemm_kernel, dim3((Cn / BNt) * (NT / BMt)), dim3(256), 0, stream,
                     (const unsigned short*)xin, Wt, Wb, fbuf);
  hipLaunchKernelGGL(epilogue_kernel, dim3(NT), dim3(256), 0, stream,
                     xbf, fbuf, hpost, hres, out);
}

// Round 9
// 164.184 us; speedup vs baseline: 1.0608x; 1.0608x over previous
//
#include <hip/hip_runtime.h>
#include <hip/hip_bf16.h>

#define HCn 4
#define Cn 2048
#define Dn (HCn*Cn)       // 8192
#define NLg 24            // HC*HC + 2*HC
#define TMAXn 8

typedef short bf16x8 __attribute__((ext_vector_type(8)));
typedef float f32x4 __attribute__((ext_vector_type(4)));

__device__ __forceinline__ unsigned int pk2(float a, float b) {
  union { __hip_bfloat162 h; unsigned int u; } v;
  v.h = __float22bfloat162_rn(float2{a, b});
  return v.u;
}
__device__ __forceinline__ unsigned short f2bfu(float a) {
  union { __hip_bfloat16 h; unsigned short u; } v;
  v.h = __float2bfloat16(a);
  return v.u;
}
__device__ __forceinline__ float bf2f(unsigned int u16) {
  union { float f; unsigned int x; } v;
  v.x = u16 << 16;
  return v.f;
}
__device__ __forceinline__ float sigm(float z) { return 1.0f / (1.0f + expf(-z)); }

__device__ __forceinline__ void gload_lds16(const void* g, void* l) {
  __builtin_amdgcn_global_load_lds((__attribute__((address_space(1))) void*)(g),
                                   (__attribute__((address_space(3))) void*)(l),
                                   16, 0, 0);
}

// ---------------- Kernel 0: phi [8192][24] -> phiB B-fragment layout (bf16) ----------
__global__ __launch_bounds__(128) void phib_kernel(const float* __restrict__ phi,
                                                   unsigned short* __restrict__ phiB) {
  int tid = threadIdx.x;
  int nt = tid >> 6, lane = tid & 63;
  int ks = blockIdx.x;
  int col = nt * 16 + (lane & 15);
  int kb = ks * 32 + (lane >> 4) * 8;
  float v[8];
#pragma unroll
  for (int e = 0; e < 8; ++e)
    v[e] = (col < NLg) ? phi[(size_t)(kb + e) * NLg + col] : 0.f;
  uint4 o = { pk2(v[0], v[1]), pk2(v[2], v[3]), pk2(v[4], v[5]), pk2(v[6], v[7]) };
  *(uint4*)&phiB[((size_t)(ks * 2 + nt) * 64 + lane) * 8] = o;
}

// ------- Kernel 1: split-K logits partials. 1024 blocks = 256 tok-groups x 4 K-chunks.
__global__ __launch_bounds__(512) void logits_kernel(
    const float* __restrict__ x, const unsigned short* __restrict__ phiB,
    float* __restrict__ pbuf) {
  __shared__ float lgp[8][16][33];
  __shared__ float ssp[8][16];

  int tid = threadIdx.x, lane = tid & 63, wid = tid >> 6;
  int g = blockIdx.x >> 2;
  int kc = blockIdx.x & 3;
  long t0 = (long)g * 16;
  int l15 = lane & 15, kg = lane >> 4;

  int kbase = kc * 2048 + wid * 256;
  const float* xr = x + (size_t)(t0 + l15) * Dn + kbase + kg * 8;
  const bf16x8* pB = (const bf16x8*)phiB + (size_t)(kbase >> 5) * 128 + lane;

  float ss = 0.f;
  f32x4 acc0 = {0.f,0.f,0.f,0.f}, acc1 = {0.f,0.f,0.f,0.f};

  float4 A0[3], A1[3]; bf16x8 Bv0[3], Bv1[3];
#define LOADIT(IT, S) {                          \
    A0[S] = *(const float4*)(xr + (IT) * 32);    \
    A1[S] = *(const float4*)(xr + (IT) * 32 + 4);\
    Bv0[S] = pB[(IT) * 128];                     \
    Bv1[S] = pB[(IT) * 128 + 64]; }
#define PROCIT(S) {                                                           \
    float4 P0 = A0[S], P1 = A1[S];                                            \
    ss += P0.x*P0.x + P0.y*P0.y + P0.z*P0.z + P0.w*P0.w;                      \
    ss += P1.x*P1.x + P1.y*P1.y + P1.z*P1.z + P1.w*P1.w;                      \
    uint4 u_ = { pk2(P0.x,P0.y), pk2(P0.z,P0.w), pk2(P1.x,P1.y), pk2(P1.z,P1.w) }; \
    bf16x8 a_ = *(bf16x8*)&u_;                                                \
    acc0 = __builtin_amdgcn_mfma_f32_16x16x32_bf16(a_, Bv0[S], acc0, 0, 0, 0);\
    acc1 = __builtin_amdgcn_mfma_f32_16x16x32_bf16(a_, Bv1[S], acc1, 0, 0, 0); }

  LOADIT(0, 0); LOADIT(1, 1);
#pragma unroll
  for (int it = 0; it < 8; ++it) {
    if (it < 6) LOADIT(it + 2, (it + 2) % 3);
    PROCIT(it % 3);
  }
#undef LOADIT
#undef PROCIT

  ss += __shfl_xor(ss, 16); ss += __shfl_xor(ss, 32);
  if (kg == 0) ssp[wid][l15] = ss;
#pragma unroll
  for (int e = 0; e < 4; ++e) {
    int tok = kg * 4 + e;
    lgp[wid][tok][l15] = acc0[e];
    lgp[wid][tok][16 + l15] = acc1[e];
  }
  __syncthreads();

  for (int q = tid; q < 16 * 25; q += 512) {
    int tk = q / 25, j = q % 25;
    float v = 0.f;
    if (j < 24) {
#pragma unroll
      for (int w = 0; w < 8; ++w) v += lgp[w][tk][j];
    } else {
#pragma unroll
      for (int w = 0; w < 8; ++w) v += ssp[w][tk];
    }
    pbuf[(size_t)(t0 + tk) * 100 + kc * 25 + j] = v;
  }
}

// ------- Kernel 1b: finalize — sum 4 K-chunks, sigmoid/Sinkhorn, emit coeffs ---------
__global__ __launch_bounds__(256) void finalize_kernel(
    const float* __restrict__ pbuf, const float* __restrict__ bb,
    const float* __restrict__ apre_p, const float* __restrict__ apost_p,
    const float* __restrict__ ares_p, float* __restrict__ hpre,
    float* __restrict__ hpost, float* __restrict__ hres) {
  long t = (long)blockIdx.x * 256 + threadIdx.x;
  const float* pt = pbuf + (size_t)t * 100;
  float lg[25];
#pragma unroll
  for (int j = 0; j < 25; ++j)
    lg[j] = pt[j] + pt[25 + j] + pt[50 + j] + pt[75 + j];
  float r = rsqrtf(lg[24] / (float)Dn + 1e-6f);
  float apre = apre_p[0], apost = apost_p[0], ares = ares_p[0];
#pragma unroll
  for (int j = 0; j < NLg; ++j) lg[j] = r * lg[j] + bb[j];
#pragma unroll
  for (int j = 0; j < 4; ++j) hpre[t * 4 + j] = sigm(apre * lg[j]) + 1e-4f;
#pragma unroll
  for (int j = 0; j < 4; ++j) hpost[t * 4 + j] = 2.0f * sigm(apost * lg[4 + j]);
  float m[16];
#pragma unroll
  for (int q = 0; q < 16; ++q) m[q] = expf(ares * lg[8 + q]);
  for (int it = 0; it < TMAXn; ++it) {
#pragma unroll
    for (int o = 0; o < 4; ++o) {
      float rs = m[o*4] + m[o*4+1] + m[o*4+2] + m[o*4+3] + 1e-6f;
      m[o*4] /= rs; m[o*4+1] /= rs; m[o*4+2] /= rs; m[o*4+3] /= rs;
    }
#pragma unroll
    for (int i = 0; i < 4; ++i) {
      float cs = m[i] + m[4+i] + m[8+i] + m[12+i] + 1e-6f;
      m[i] /= cs; m[4+i] /= cs; m[8+i] /= cs; m[12+i] /= cs;
    }
  }
#pragma unroll
  for (int q = 0; q < 16; ++q) hres[t * 16 + q] = m[q];
}

// ------- Kernel 1c: x_in = sum_hc h_pre[hc]*x[hc,:] (bf16), one token per block -----
__global__ __launch_bounds__(256) void xin_kernel(
    const float* __restrict__ x, const float* __restrict__ hpre,
    unsigned int* __restrict__ xin) {
  long t = blockIdx.x;
  int tid = threadIdx.x;
  float h0 = hpre[t * 4 + 0], h1 = hpre[t * 4 + 1];
  float h2 = hpre[t * 4 + 2], h3 = hpre[t * 4 + 3];
  const float4* xt = (const float4*)(x + (size_t)t * Dn);
  uint2* xo = (uint2*)xin + (size_t)t * (Cn / 4);
#pragma unroll
  for (int it = 0; it < 2; ++it) {
    int c4 = it * 256 + tid;
    float4 v0 = xt[c4];
    float4 v1 = xt[c4 + 512];
    float4 v2 = xt[c4 + 1024];
    float4 v3 = xt[c4 + 1536];
    float sx = h0*v0.x + h1*v1.x + h2*v2.x + h3*v3.x;
    float sy = h0*v0.y + h1*v1.y + h2*v2.y + h3*v3.y;
    float sz = h0*v0.z + h1*v1.z + h2*v2.z + h3*v3.z;
    float sw = h0*v0.w + h1*v1.w + h2*v2.w + h3*v3.w;
    uint2 o; o.x = pk2(sx, sy); o.y = pk2(sz, sw);
    xo[c4] = o;
  }
}

// ---------------- Kernel 2: W (K x N, f32) -> Wt (N x K, bf16) ----------------
__global__ __launch_bounds__(256) void wtrans_kernel(const float* __restrict__ W,
                                                     unsigned short* __restrict__ Wt) {
  __shared__ float tile[64][65];
  int kb = blockIdx.y * 64, nb = blockIdx.x * 64;
  int tr = threadIdx.x >> 4;
  int tc = threadIdx.x & 15;
#pragma unroll
  for (int rr = 0; rr < 64; rr += 16) {
    float4 v = *(const float4*)&W[(size_t)(kb + tr + rr) * Cn + nb + tc * 4];
    tile[tr + rr][tc * 4 + 0] = v.x; tile[tr + rr][tc * 4 + 1] = v.y;
    tile[tr + rr][tc * 4 + 2] = v.z; tile[tr + rr][tc * 4 + 3] = v.w;
  }
  __syncthreads();
#pragma unroll
  for (int rr = 0; rr < 64; rr += 16) {
    int n = nb + tr + rr;
    uint2 o;
    o.x = pk2(tile[tc * 4 + 0][tr + rr], tile[tc * 4 + 1][tr + rr]);
    o.y = pk2(tile[tc * 4 + 2][tr + rr], tile[tc * 4 + 3][tr + rr]);
    *(uint2*)&Wt[(size_t)n * Cn + kb + tc * 4] = o;
  }
}

// ---- Kernel 3: bf16 MFMA GEMM, BK=64 dbuf + XOR-swizzled LDS + counted-vmcnt pipeline
// f = x_in @ W^T(bf16) + Wb, written bf16.
#define BMt 128
#define BNt 128
#define BKt 64
#define GK Cn
__global__ __launch_bounds__(256) void gemm_kernel(
    const unsigned short* __restrict__ xin, const unsigned short* __restrict__ Wt,
    const float* __restrict__ Wb, unsigned short* __restrict__ f) {
  __shared__ __align__(16) unsigned short As[2][BMt * BKt];  // 2 x 16 KB
  __shared__ __align__(16) unsigned short Bs[2][BNt * BKt];  // 2 x 16 KB
  int tid = threadIdx.x;
  int lane = tid & 63, wid = tid >> 6;
  int wr = wid >> 1, wc = wid & 1;
  int l15 = lane & 15, kg = lane >> 4;
  int wg = blockIdx.x;
  wg = (wg & 7) * 64 + (wg >> 3);   // XCD swizzle (512 % 8 == 0, bijective)
  int bx = wg & 15, by = wg >> 4;

  f32x4 acc[4][4];
#pragma unroll
  for (int i = 0; i < 4; ++i)
#pragma unroll
    for (int j = 0; j < 4; ++j) acc[i][j] = {0.f, 0.f, 0.f, 0.f};

  const char* Ab = (const char*)xin + (size_t)by * BMt * (GK * 2);
  const char* Bb = (const char*)Wt + (size_t)bx * BNt * (GK * 2);

  // staging: 4 issues per matrix; row-major [128][128B], swizzled GLOBAL col, linear LDS
  int soff[4]; size_t sgl[4];
#pragma unroll
  for (int i = 0; i < 4; ++i) {
    int off = tid * 16 + i * 4096;
    int row = off >> 7, col = off & 127;
    int scol = col ^ ((row & 7) << 4);
    soff[i] = off;
    sgl[i] = (size_t)row * (GK * 2) + scol;
  }
#define STAGEG(BUF, K0) {                                                      \
    _Pragma("unroll")                                                          \
    for (int i_ = 0; i_ < 4; ++i_)                                             \
      gload_lds16(Ab + sgl[i_] + (size_t)(K0) * 2, (char*)As[BUF] + soff[i_]); \
    _Pragma("unroll")                                                          \
    for (int i_ = 0; i_ < 4; ++i_)                                             \
      gload_lds16(Bb + sgl[i_] + (size_t)(K0) * 2, (char*)Bs[BUF] + soff[i_]); }

  // fragment read byte-offsets (swizzled), per fm/fn and ks
  int aoff[4][2], boff[4][2];
#pragma unroll
  for (int fm = 0; fm < 4; ++fm) {
    int ar = wr * 64 + fm * 16 + l15;
    int br = wc * 64 + fm * 16 + l15;
#pragma unroll
    for (int ks = 0; ks < 2; ++ks) {
      int c = ks * 64 + kg * 16;
      aoff[fm][ks] = ar * 128 + (c ^ ((ar & 7) << 4));
      boff[fm][ks] = br * 128 + (c ^ ((br & 7) << 4));
    }
  }

  STAGEG(0, 0);
  asm volatile("s_waitcnt vmcnt(0)" ::: "memory");
  __builtin_amdgcn_s_barrier();

  for (int t = 0; t < GK / BKt; ++t) {
    int cur = t & 1;
    if (t < GK / BKt - 1) STAGEG(cur ^ 1, (t + 1) * BKt);
#pragma unroll
    for (int ks = 0; ks < 2; ++ks) {
      bf16x8 av[4], bv[4];
#pragma unroll
      for (int fm = 0; fm < 4; ++fm)
        av[fm] = *(const bf16x8*)((const char*)As[cur] + aoff[fm][ks]);
#pragma unroll
      for (int fn = 0; fn < 4; ++fn)
        bv[fn] = *(const bf16x8*)((const char*)Bs[cur] + boff[fn][ks]);
#pragma unroll
      for (int fm = 0; fm < 4; ++fm)
#pragma unroll
        for (int fn = 0; fn < 4; ++fn)
          acc[fm][fn] = __builtin_amdgcn_mfma_f32_16x16x32_bf16(av[fm], bv[fn], acc[fm][fn], 0, 0, 0);
    }
    asm volatile("s_waitcnt vmcnt(0)" ::: "memory");
    __builtin_amdgcn_s_barrier();
  }

  int m0 = by * BMt + wr * 64;
  int n0 = bx * BNt + wc * 64;
#pragma unroll
  for (int fm = 0; fm < 4; ++fm) {
#pragma unroll
    for (int e = 0; e < 4; ++e) {
      int t = m0 + fm * 16 + kg * 4 + e;
      unsigned short* ft = f + (size_t)t * Cn;
#pragma unroll
      for (int fn = 0; fn < 4; ++fn) {
        int c = n0 + fn * 16 + l15;
        ft[c] = f2bfu(acc[fm][fn][e] + Wb[c]);
      }
    }
  }
}

// ---------------- Kernel 4: streaming epilogue (one token per block) -----------------
// out[t,o,c] = sum_i hres[t,o,i]*x[t,i,c] + hpost[t,o]*f[t,c]   (NT stores)
__global__ __launch_bounds__(256) void epilogue_kernel(
    const float* __restrict__ x, const unsigned short* __restrict__ f,
    const float* __restrict__ hpost, const float* __restrict__ hres,
    float* __restrict__ out) {
  long t = blockIdx.x;
  int tid = threadIdx.x;
  float hq[4], hr[16];
#pragma unroll
  for (int o = 0; o < 4; ++o) hq[o] = hpost[t * 4 + o];
#pragma unroll
  for (int q = 0; q < 16; ++q) hr[q] = hres[t * 16 + q];
  const float4* xt = (const float4*)(x + (size_t)t * Dn);
  const uint2* ft = (const uint2*)(f + (size_t)t * Cn);
  float* ot = out + (size_t)t * Dn;
#pragma unroll
  for (int it = 0; it < 2; ++it) {
    int c4 = it * 256 + tid;
    float4 x0 = xt[c4], x1 = xt[c4 + 512], x2 = xt[c4 + 1024], x3 = xt[c4 + 1536];
    uint2 fu = ft[c4];
    float4 fv = { bf2f(fu.x & 0xffffu), bf2f(fu.x >> 16),
                  bf2f(fu.y & 0xffffu), bf2f(fu.y >> 16) };
#pragma unroll
    for (int o = 0; o < 4; ++o) {
      float a = hr[o*4+0], b = hr[o*4+1], c = hr[o*4+2], d = hr[o*4+3], q = hq[o];
      f32x4 r;
      r[0] = q*fv.x + a*x0.x + b*x1.x + c*x2.x + d*x3.x;
      r[1] = q*fv.y + a*x0.y + b*x1.y + c*x2.y + d*x3.y;
      r[2] = q*fv.z + a*x0.z + b*x1.z + c*x2.z + d*x3.z;
      r[3] = q*fv.w + a*x0.w + b*x1.w + c*x2.w + d*x3.w;
      __builtin_nontemporal_store(r, (f32x4*)&ot[(size_t)o * Cn + c4 * 4]);
    }
  }
}

extern "C" void kernel_launch(void* const* d_in, const int* in_sizes, int n_in,
                              void* d_out, int out_size, void* d_ws, size_t ws_size,
                              hipStream_t stream) {
  const float* x     = (const float*)d_in[0];
  const float* phi   = (const float*)d_in[1];
  const float* b     = (const float*)d_in[2];
  const float* apre  = (const float*)d_in[3];
  const float* apost = (const float*)d_in[4];
  const float* ares  = (const float*)d_in[5];
  const float* W     = (const float*)d_in[6];
  const float* Wb    = (const float*)d_in[7];
  float* out = (float*)d_out;

  int NT = in_sizes[0] / Dn;   // 4096 tokens
  char* ws = (char*)d_ws;
  size_t off = 0;
  unsigned int*   xin  = (unsigned int*)(ws + off);   off += (size_t)NT * Cn * 2;   // 16 MB
  unsigned short* Wt   = (unsigned short*)(ws + off); off += (size_t)Cn * Cn * 2;   // 8 MB
  float* hpre  = (float*)(ws + off); off += (size_t)NT * 4 * 4;
  float* hpost = (float*)(ws + off); off += (size_t)NT * 4 * 4;
  float* hres  = (float*)(ws + off); off += (size_t)NT * 16 * 4;
  unsigned short* phiB = (unsigned short*)(ws + off); off += (size_t)Dn * 32 * 2;   // 512 KB
  float* pbuf  = (float*)(ws + off); off += (size_t)NT * 100 * 4;                   // 1.6 MB
  unsigned short* fbuf = (unsigned short*)(ws + off); off += (size_t)NT * Cn * 2;   // 16 MB

  hipLaunchKernelGGL(phib_kernel, dim3(Dn / 32), dim3(128), 0, stream, phi, phiB);
  hipLaunchKernelGGL(logits_kernel, dim3((NT / 16) * 4), dim3(512), 0, stream,
                     x, phiB, pbuf);
  hipLaunchKernelGGL(finalize_kernel, dim3(NT / 256), dim3(256), 0, stream,
                     pbuf, b, apre, apost, ares, hpre, hpost, hres);
  hipLaunchKernelGGL(xin_kernel, dim3(NT), dim3(256), 0, stream, x, hpre, xin);
  hipLaunchKernelGGL(wtrans_kernel, dim3(Cn / 64, Cn / 64), dim3(256), 0, stream, W, Wt);
  hipLaunchKernelGGL(gemm_kernel, dim3((Cn / BNt) * (NT / BMt)), dim3(256), 0, stream,
                     (const unsigned short*)xin, Wt, Wb, fbuf);
  hipLaunchKernelGGL(epilogue_kernel, dim3(NT), dim3(256), 0, stream,
                     x, fbuf, hpost, hres, out);
}